// Round 1
// baseline (278.530 us; speedup 1.0000x reference)
//
#include <hip/hip_runtime.h>

// Volume-rendering composite: B=65536 rays, N=128 samples/ray.
//   alpha_i = 1 - exp(-sigma_i * delta_i)
//   T_i     = prod_{j<i} (1 - alpha_j) = exp(-sum_{j<i} sigma_j*delta_j)
//   w_i     = alpha_i * T_i = exp(-S_i) - exp(-S_{i+1}),  S_i = prefix sum
// Outputs per ray: rgb(3) | depth(1) | normal(3) | acc(1)  -> [B, 8] f32
//
// Strategy: one 64-lane wave per ray, 2 samples per lane. Wave-wide shuffle
// prefix-sum in log space replaces the sequential cumprod. All loads are
// wave-contiguous (float2 granularity). Memory-bound: ~288 MB read.

constexpr int RAYS = 65536;
constexpr int NS   = 128;

__global__ __launch_bounds__(256) void render_composite_kernel(
    const float* __restrict__ density,   // [B, N]
    const float* __restrict__ deltas,    // [B, N]
    const float* __restrict__ zs,        // [B, N]
    const float* __restrict__ rgbs,      // [B, N, 3]
    const float* __restrict__ normals,   // [B, N, 3]
    float* __restrict__ out)             // [B, 8]
{
    const int lane = threadIdx.x & 63;
    const int wave = threadIdx.x >> 6;                 // 4 waves / block
    const int ray  = blockIdx.x * 4 + wave;
    if (ray >= RAYS) return;

    const size_t row  = (size_t)ray * NS;
    const size_t row3 = (size_t)ray * NS * 3;

    // ---- scalar per-sample inputs: 2 samples per lane, float2 loads ----
    const float2 d  = reinterpret_cast<const float2*>(density + row)[lane];
    const float2 dl = reinterpret_cast<const float2*>(deltas  + row)[lane];
    const float2 z  = reinterpret_cast<const float2*>(zs      + row)[lane];

    const float s0 = d.x * dl.x;     // sigma*delta, sample 2*lane
    const float s1 = d.y * dl.y;     // sample 2*lane+1
    const float slocal = s0 + s1;

    // ---- wave-wide inclusive prefix sum of slocal (6 shuffle steps) ----
    float prefix = slocal;
    #pragma unroll
    for (int off = 1; off < 64; off <<= 1) {
        float up = __shfl_up(prefix, off, 64);
        if (lane >= off) prefix += up;
    }
    const float S_base = prefix - slocal;              // exclusive prefix

    // ---- transmittance endpoints -> weights ----
    const float e0 = __expf(-S_base);
    const float e1 = __expf(-(S_base + s0));
    const float e2 = __expf(-(S_base + s0 + s1));
    const float w0 = e0 - e1;
    const float w1 = e1 - e2;

    // ---- rgb / normal fragments: 6 floats per lane as 3x float2 ----
    const float2* rg2 = reinterpret_cast<const float2*>(rgbs    + row3) + lane * 3;
    const float2* nm2 = reinterpret_cast<const float2*>(normals + row3) + lane * 3;
    const float2 ra = rg2[0], rb = rg2[1], rc = rg2[2];
    const float2 na = nm2[0], nb = nm2[1], nc = nm2[2];
    // sample0 = (a.x, a.y, b.x); sample1 = (b.y, c.x, c.y)

    float acc_r = w0 * ra.x + w1 * rb.y;
    float acc_g = w0 * ra.y + w1 * rc.x;
    float acc_b = w0 * rb.x + w1 * rc.y;
    float acc_nr = w0 * na.x + w1 * nb.y;
    float acc_ng = w0 * na.y + w1 * nc.x;
    float acc_nb = w0 * nb.x + w1 * nc.y;
    float acc_w  = w0 + w1;
    float acc_wz = w0 * z.x + w1 * z.y;

    // ---- wave butterfly reductions (8 values, 6 steps each) ----
    #pragma unroll
    for (int off = 32; off > 0; off >>= 1) {
        acc_r  += __shfl_xor(acc_r,  off, 64);
        acc_g  += __shfl_xor(acc_g,  off, 64);
        acc_b  += __shfl_xor(acc_b,  off, 64);
        acc_nr += __shfl_xor(acc_nr, off, 64);
        acc_ng += __shfl_xor(acc_ng, off, 64);
        acc_nb += __shfl_xor(acc_nb, off, 64);
        acc_w  += __shfl_xor(acc_w,  off, 64);
        acc_wz += __shfl_xor(acc_wz, off, 64);
    }

    if (lane == 0) {
        const float depth = acc_wz / (acc_w + 1e-8f);
        float4* o = reinterpret_cast<float4*>(out + (size_t)ray * 8);
        o[0] = make_float4(acc_r, acc_g, acc_b, depth);
        o[1] = make_float4(acc_nr, acc_ng, acc_nb, acc_w);
    }
}

extern "C" void kernel_launch(void* const* d_in, const int* in_sizes, int n_in,
                              void* d_out, int out_size, void* d_ws, size_t ws_size,
                              hipStream_t stream) {
    const float* density = (const float*)d_in[0];
    const float* deltas  = (const float*)d_in[1];
    const float* zs      = (const float*)d_in[2];
    const float* rgbs    = (const float*)d_in[3];
    const float* normals = (const float*)d_in[4];
    float* out = (float*)d_out;

    const int waves_per_block = 4;                      // 256 threads
    const int grid = RAYS / waves_per_block;            // 16384 blocks
    render_composite_kernel<<<grid, 256, 0, stream>>>(
        density, deltas, zs, rgbs, normals, out);
}